// Round 16
// baseline (268.306 us; speedup 1.0000x reference)
//
#include <hip/hip_runtime.h>

// ---------- types ----------
typedef _Float16 f16;
typedef _Float16 f16x4 __attribute__((ext_vector_type(4)));
typedef _Float16 f16x8 __attribute__((ext_vector_type(8)));
typedef float    f32x4 __attribute__((ext_vector_type(4)));

#define N_ROWS 100000
#define NTILE 1563        // 1563 * 64 = 100032 padded rows
#define GRID 521          // 521 blocks * 3 tiles = 1563 exactly
#define TPB 256
#define LSX 264           // X tile f16 row stride: 256 data + 8 pad
#define LSH1 136
#define LSH2 72

// ws: fragment-linear weights.
// W1F[((M*8+it)*64 + lane)*8 + j] = Wcomb1[col = M*16+(lane&15)][k = it*32+(lane>>4)*8+j]
// W2F[((t*4+kc)*64 + lane)*8 + j] = Wcomb2[col(t)][k = kc*32+(lane>>4)*8+j]
#define W1F_OFF 0
#define W1F_BYTES (256 * 256 * 2)
#define W2F_OFF W1F_BYTES

// arena: TWO X buffers (cross-tile double buffer). h1s/h2s overlay the consumed one.
#define XHALF 33792       // 64*264*2
#define ARENA (2 * XHALF)
#define H1OFF 0           // within cur: 64*136*2 = 17408
#define H2OFF 17408       // within cur: 64*72*2  =  9216 -> 26624 <= XHALF

// ---------- prep: fragment-linear combined f16 weights ----------
__global__ void prep_w(const float* __restrict__ wz1, const float* __restrict__ wh1,
                       const float* __restrict__ wz2, const float* __restrict__ wh2,
                       f16* __restrict__ W1F, f16* __restrict__ W2F) {
    const int b = blockIdx.x, tid = threadIdx.x;
    if (b < 32) {                                  // W1F: 8192 threads, 8 f16 each
        int idx = b * 256 + tid;                   // (M*8+it)*64 + lane
        int l = idx & 63, itm = idx >> 6;
        int it = itm & 7, M = itm >> 3;
        int ln = l & 15, q = l >> 4;
        int col = M * 16 + ln;
        int k0 = it * 32 + q * 8;
        const float* w = (col < 128) ? wz1 : wh1;
        int cc = col & 127;
        f16x8 v;
#pragma unroll
        for (int j = 0; j < 8; ++j) {
            int k = k0 + j;
            v[j] = (f16)(w[k * 128 + cc] + w[384 * 128 + k * 128 + cc]);
        }
        *(f16x8*)&W1F[idx * 8] = v;
    } else {                                       // W2F: 2048 threads, 8 f16 each
        int idx = (b - 32) * 256 + tid;            // (t*4+kc)*64 + lane
        if (idx >= 2048) return;
        int l = idx & 63, tkc = idx >> 6;
        int kc = tkc & 3, t = tkc >> 2;
        int ln = l & 15, q = l >> 4;
        int col = (t < 4) ? (16 * t + ln) : (64 + 16 * (t - 4) + ln);
        int k0 = kc * 32 + q * 8;
        const float* w = (col < 64) ? wz2 : wh2;
        int cc = col & 63;
        f16x8 v;
#pragma unroll
        for (int j = 0; j < 8; ++j) {
            int k = k0 + j;
            v[j] = (f16)(w[k * 64 + cc] + w[192 * 64 + k * 64 + cc]);
        }
        *(f16x8*)&W2F[idx * 8] = v;
    }
}

// gate: relu( tanh(hp) * (1 - sigmoid(zp)) ) with a single v_rcp.
__device__ __forceinline__ float gate(float zp, float hp) {
    float e2h = __expf(2.0f * fminf(hp, 15.0f));
    float ez  = __expf(zp);
    float r   = __builtin_amdgcn_rcpf((e2h + 1.0f) * (1.0f + ez));
    return fmaxf((e2h - 1.0f) * r, 0.0f);
}

// ---------- fused: 3 tiles/block, cross-tile double-buffered LDS, 2 blocks/CU (256-reg tier).
// K-loop of tile t: barrier-free; streams tile t+1 into the other buffer via a
// 3-slice register ring (x-load cover = 3 K-iters ~ 900+ cy >= HBM latency).
__global__ __launch_bounds__(TPB, 2) void fused(
    const float* __restrict__ x,
    const f16* __restrict__ W1F, const f16* __restrict__ W2F,
    const float* __restrict__ bz1, const float* __restrict__ bh1,
    const float* __restrict__ bz2, const float* __restrict__ bh2,
    const float* __restrict__ wl1, const float* __restrict__ bl1,
    const float* __restrict__ wl2, const float* __restrict__ bl2,
    float* __restrict__ out)
{
    __shared__ __align__(16) char arena[ARENA];
    const int tid = threadIdx.x, lane = tid & 63, wave = tid >> 6;
    const int ln = lane & 15, quad = lane >> 4;

    // staging map: 4 threads/row, 8 f32 per slice
    const int xr = tid >> 2, xcg = tid & 3;

    // P1: wave w owns m-tiles {w, w+4, w+8, w+12}
    const f16* wb0 = W1F + (size_t)wave * 4096 + (size_t)lane * 8;   // + mi*16384 + s*512

    // ---- hoisted tile-invariants (256-reg tier: no spill) ----
    f16x8 w2f[2][4];
#pragma unroll
    for (int kc = 0; kc < 4; ++kc) {
        w2f[0][kc] = *(const f16x8*)(W2F + ((size_t)((wave    ) * 4 + kc) * 64 + lane) * 8);
        w2f[1][kc] = *(const f16x8*)(W2F + ((size_t)((wave + 4) * 4 + kc) * 64 + lane) * 8);
    }
    const float blv = bl1[ln], wlv = wl2[ln], bl2v = bl2[0];
    f16x8 bfr[2];
#pragma unroll
    for (int kc = 0; kc < 2; ++kc)
#pragma unroll
        for (int j = 0; j < 8; ++j)
            bfr[kc][j] = (f16)wl1[(32 * kc + 8 * quad + j) * 16 + ln];

    // x row pointer for tile tt (clamped)
    auto xrow = [&](int tt) {
        int r = tt * 64 + xr; if (r >= N_ROWS) r = N_ROWS - 1;
        return x + (size_t)r * 256 + (xcg << 3);
    };

    // ---- prologue: stage tile[0] fully into buf0 (two 4-slice halves) ----
    {
        const float* xp = xrow(blockIdx.x);
        f16* b0 = (f16*)arena;
#pragma unroll
        for (int half = 0; half < 2; ++half) {
            f32x4 a[4], c[4];
#pragma unroll
            for (int kc = 0; kc < 4; ++kc) {
                a[kc] = __builtin_nontemporal_load((const f32x4*)(xp + (half * 4 + kc) * 32));
                c[kc] = __builtin_nontemporal_load((const f32x4*)(xp + (half * 4 + kc) * 32 + 4));
            }
#pragma unroll
            for (int kc = 0; kc < 4; ++kc)
                *(f16x8*)&b0[xr * LSX + (half * 4 + kc) * 32 + (xcg << 3)] =
                    (f16x8){(f16)a[kc][0],(f16)a[kc][1],(f16)a[kc][2],(f16)a[kc][3],
                            (f16)c[kc][0],(f16)c[kc][1],(f16)c[kc][2],(f16)c[kc][3]};
        }
    }
    __syncthreads();

#pragma unroll 1
    for (int t = 0; t < 3; ++t) {
        const int tt = blockIdx.x + GRID * t;
        f16* cur = (f16*)(arena + (t & 1) * XHALF);
        f16* nxt = (f16*)(arena + ((t + 1) & 1) * XHALF);
        const bool hn = (t < 2);
        const float* xpn = hn ? xrow(tt + GRID) : (const float*)nullptr;

        // 3-slice prefetch ring for next tile
        f32x4 pa[3], pb[3];
        if (hn) {
#pragma unroll
            for (int d = 0; d < 3; ++d) {
                pa[d] = __builtin_nontemporal_load((const f32x4*)(xpn + d * 32));
                pb[d] = __builtin_nontemporal_load((const f32x4*)(xpn + d * 32 + 4));
            }
        }

        f32x4 acc[4][4];                               // [mi][nt], 64 AGPR
#pragma unroll
        for (int a = 0; a < 4; ++a)
#pragma unroll
            for (int b = 0; b < 4; ++b) acc[a][b] = (f32x4){0.f, 0.f, 0.f, 0.f};

        f16x8 afc[4], afn[4];
#pragma unroll
        for (int mi = 0; mi < 4; ++mi)
            afc[mi] = *(const f16x8*)(wb0 + mi * 16384);

        // ---- K-loop: barrier-free; commit next-tile slice s, refill ring slot with s+3 ----
#pragma unroll
        for (int s = 0; s < 8; ++s) {
            if (s < 7) {
#pragma unroll
                for (int mi = 0; mi < 4; ++mi)
                    afn[mi] = *(const f16x8*)(wb0 + mi * 16384 + (s + 1) * 512);
            }
            if (hn) {
                const int sl = s % 3;
                *(f16x8*)&nxt[xr * LSX + s * 32 + (xcg << 3)] =
                    (f16x8){(f16)pa[sl][0],(f16)pa[sl][1],(f16)pa[sl][2],(f16)pa[sl][3],
                            (f16)pb[sl][0],(f16)pb[sl][1],(f16)pb[sl][2],(f16)pb[sl][3]};
                if (s + 3 < 8) {
                    pa[sl] = __builtin_nontemporal_load((const f32x4*)(xpn + (s + 3) * 32));
                    pb[sl] = __builtin_nontemporal_load((const f32x4*)(xpn + (s + 3) * 32 + 4));
                }
            }
            f16x8 bf[4];
#pragma unroll
            for (int nt = 0; nt < 4; ++nt)
                bf[nt] = *(const f16x8*)&cur[(16 * nt + ln) * LSX + s * 32 + quad * 8];
#pragma unroll
            for (int nt = 0; nt < 4; ++nt)
#pragma unroll
                for (int mi = 0; mi < 4; ++mi)
                    acc[mi][nt] = __builtin_amdgcn_mfma_f32_16x16x32_f16(afc[mi], bf[nt], acc[mi][nt], 0, 0, 0);
#pragma unroll
            for (int mi = 0; mi < 4; ++mi) afc[mi] = afn[mi];
        }
        __syncthreads();                               // cur bf reads done; gates overlay cur

        // P1 epilogue: gates -> h1s (overlay cur).
        f16* h1s = (f16*)((char*)cur + H1OFF);
        f16* h2s = (f16*)((char*)cur + H2OFF);
#pragma unroll
        for (int zi = 0; zi < 2; ++zi) {
            const int jg0 = 16 * (wave + 4 * zi) + (quad << 2);
            const float4 zb = *(const float4*)(bz1 + jg0);
            const float4 hb = *(const float4*)(bh1 + jg0);
#pragma unroll
            for (int nt = 0; nt < 4; ++nt) {
                const int row = 16 * nt + ln;
                f16x4 pk;
#pragma unroll
                for (int i = 0; i < 4; ++i)
                    pk[i] = (f16)gate(acc[zi][nt][i] + (&zb.x)[i],
                                      acc[zi + 2][nt][i] + (&hb.x)[i]);
                *(f16x4*)&h1s[row * LSH1 + jg0] = pk;
            }
        }
        __syncthreads();

        // ---- P2: h2 = gates(h1 @ W2) ----
        f32x4 acc2[2][4];
#pragma unroll
        for (int a = 0; a < 2; ++a)
#pragma unroll
            for (int b = 0; b < 4; ++b) acc2[a][b] = (f32x4){0.f, 0.f, 0.f, 0.f};
#pragma unroll
        for (int kc = 0; kc < 4; ++kc) {
            f16x8 bf[4];
#pragma unroll
            for (int nt = 0; nt < 4; ++nt)
                bf[nt] = *(const f16x8*)&h1s[(16 * nt + ln) * LSH1 + kc * 32 + quad * 8];
#pragma unroll
            for (int m = 0; m < 2; ++m)
#pragma unroll
                for (int nt = 0; nt < 4; ++nt)
                    acc2[m][nt] = __builtin_amdgcn_mfma_f32_16x16x32_f16(w2f[m][kc], bf[nt], acc2[m][nt], 0, 0, 0);
        }
        // h2s disjoint from h1s: no barrier needed here
        {
            const int jg0 = 16 * wave + (quad << 2);
            const float4 zb = *(const float4*)(bz2 + jg0);
            const float4 hb = *(const float4*)(bh2 + jg0);
#pragma unroll
            for (int nt = 0; nt < 4; ++nt) {
                const int row = 16 * nt + ln;
                f16x4 pk;
#pragma unroll
                for (int i = 0; i < 4; ++i)
                    pk[i] = (f16)gate(acc2[0][nt][i] + (&zb.x)[i],
                                      acc2[1][nt][i] + (&hb.x)[i]);
                *(f16x4*)&h2s[row * LSH2 + jg0] = pk;
            }
        }
        __syncthreads();                               // h2s visible for P3

        // ---- P3: out = relu(h2 @ wl1 + bl1) @ wl2 + bl2 ----
        f32x4 acc3 = (f32x4){0.f, 0.f, 0.f, 0.f};
#pragma unroll
        for (int kc = 0; kc < 2; ++kc) {
            f16x8 af = *(const f16x8*)&h2s[(16 * wave + ln) * LSH2 + kc * 32 + quad * 8];
            acc3 = __builtin_amdgcn_mfma_f32_16x16x32_f16(af, bfr[kc], acc3, 0, 0, 0);
        }
#pragma unroll
        for (int i = 0; i < 4; ++i) {
            float v = fmaxf(acc3[i] + blv, 0.0f) * wlv;
            v += __shfl_xor(v, 1);
            v += __shfl_xor(v, 2);
            v += __shfl_xor(v, 4);
            v += __shfl_xor(v, 8);
            if (ln == 0) {
                const int row = tt * 64 + 16 * wave + (quad << 2) + i;
                if (row < N_ROWS) out[row] = v + bl2v;
            }
        }
        __syncthreads();                               // boundary: h2s reads done before next
    }                                                  // K-loop commits overwrite this buffer
}

// ---------- launch ----------
extern "C" void kernel_launch(void* const* d_in, const int* in_sizes, int n_in,
                              void* d_out, int out_size, void* d_ws, size_t ws_size,
                              hipStream_t stream) {
    const float* x   = (const float*)d_in[0];
    const float* wz1 = (const float*)d_in[3];
    const float* bz1 = (const float*)d_in[4];
    const float* wh1 = (const float*)d_in[7];
    const float* bh1 = (const float*)d_in[8];
    const float* wz2 = (const float*)d_in[9];
    const float* bz2 = (const float*)d_in[10];
    const float* wh2 = (const float*)d_in[13];
    const float* bh2 = (const float*)d_in[14];
    const float* wl1 = (const float*)d_in[15];
    const float* bl1 = (const float*)d_in[16];
    const float* wl2 = (const float*)d_in[17];
    const float* bl2 = (const float*)d_in[18];

    char* ws = (char*)d_ws;
    f16* W1F = (f16*)(ws + W1F_OFF);
    f16* W2F = (f16*)(ws + W2F_OFF);
    float* out = (float*)d_out;

    prep_w<<<40, 256, 0, stream>>>(wz1, wh1, wz2, wh2, W1F, W2F);
    fused<<<GRID, TPB, 0, stream>>>(x, W1F, W2F, bz1, bh1, bz2, bh2,
                                    wl1, bl1, wl2, bl2, out);
}

// Round 18
// 215.590 us; speedup vs baseline: 1.2445x; 1.2445x over previous
//
#include <hip/hip_runtime.h>

// ---------- types ----------
typedef _Float16 f16;
typedef _Float16 f16x4 __attribute__((ext_vector_type(4)));
typedef _Float16 f16x8 __attribute__((ext_vector_type(8)));
typedef float    f32x4 __attribute__((ext_vector_type(4)));

#define N_ROWS 100000
#define RT 1563           // 1563 * 64 = 100032 padded rows
#define TPB 256
#define LSX 264           // X tile f16 row stride: 256 data + 8 pad
#define LSH1 136
#define LSH2 72

// ws: fragment-linear weights.
// W1F[((M*8+it)*64 + lane)*8 + j] = Wcomb1[col = M*16+(lane&15)][k = it*32+(lane>>4)*8+j]
// W2F[((t*4+kc)*64 + lane)*8 + j] = Wcomb2[col(t)][k = kc*32+(lane>>4)*8+j]
#define W1F_OFF 0
#define W1F_BYTES (256 * 256 * 2)
#define W2F_OFF W1F_BYTES

// arena: X tile 64*264*2 = 33792; h1s/h2s overlay after K-loop
#define ARENA 33792
#define H1S 0             // 64*136*2 = 17408
#define H2S 17408         // 64*72*2  =  9216 -> 26624 <= ARENA

// ---------- prep: fragment-linear combined f16 weights ----------
__global__ void prep_w(const float* __restrict__ wz1, const float* __restrict__ wh1,
                       const float* __restrict__ wz2, const float* __restrict__ wh2,
                       f16* __restrict__ W1F, f16* __restrict__ W2F) {
    const int b = blockIdx.x, tid = threadIdx.x;
    if (b < 32) {                                  // W1F: 8192 threads, 8 f16 each
        int idx = b * 256 + tid;                   // (M*8+it)*64 + lane
        int l = idx & 63, itm = idx >> 6;
        int it = itm & 7, M = itm >> 3;
        int ln = l & 15, q = l >> 4;
        int col = M * 16 + ln;
        int k0 = it * 32 + q * 8;
        const float* w = (col < 128) ? wz1 : wh1;
        int cc = col & 127;
        f16x8 v;
#pragma unroll
        for (int j = 0; j < 8; ++j) {
            int k = k0 + j;
            v[j] = (f16)(w[k * 128 + cc] + w[384 * 128 + k * 128 + cc]);
        }
        *(f16x8*)&W1F[idx * 8] = v;
    } else {                                       // W2F: 2048 threads, 8 f16 each
        int idx = (b - 32) * 256 + tid;            // (t*4+kc)*64 + lane
        if (idx >= 2048) return;
        int l = idx & 63, tkc = idx >> 6;
        int kc = tkc & 3, t = tkc >> 2;
        int ln = l & 15, q = l >> 4;
        int col = (t < 4) ? (16 * t + ln) : (64 + 16 * (t - 4) + ln);
        int k0 = kc * 32 + q * 8;
        const float* w = (col < 64) ? wz2 : wh2;
        int cc = col & 63;
        f16x8 v;
#pragma unroll
        for (int j = 0; j < 8; ++j) {
            int k = k0 + j;
            v[j] = (f16)(w[k * 64 + cc] + w[192 * 64 + k * 64 + cc]);
        }
        *(f16x8*)&W2F[idx * 8] = v;
    }
}

// gate: relu( tanh(hp) * (1 - sigmoid(zp)) ) with a single v_rcp.
__device__ __forceinline__ float gate(float zp, float hp) {
    float e2h = __expf(2.0f * fminf(hp, 15.0f));
    float ez  = __expf(zp);
    float r   = __builtin_amdgcn_rcpf((e2h + 1.0f) * (1.0f + ez));
    return fmaxf((e2h - 1.0f) * r, 0.0f);
}

// ---------- fused: 64 rows/block, 4 waves, 3 blocks/CU.
// R15 base (raw s_barrier, no vmcnt drain) + DISTANCE-2 x prefetch:
// two named register sets; commit set (s&1) at slice s, refill with slice s+2.
// af prefetch issued before x refill (af slack = 1 iter, x slack = 2 iters).
__global__ __launch_bounds__(TPB, 3) void fused(
    const float* __restrict__ x,
    const f16* __restrict__ W1F, const f16* __restrict__ W2F,
    const float* __restrict__ bz1, const float* __restrict__ bh1,
    const float* __restrict__ bz2, const float* __restrict__ bh2,
    const float* __restrict__ wl1, const float* __restrict__ bl1,
    const float* __restrict__ wl2, const float* __restrict__ bl2,
    float* __restrict__ out)
{
    __shared__ __align__(16) char arena[ARENA];
    const int tid = threadIdx.x, lane = tid & 63, wave = tid >> 6;
    const int ln = lane & 15, quad = lane >> 4;
    const int r0 = blockIdx.x * 64;

    // slice staging map: 4 threads/row, 8 f32 each (cols s*32 + (tid&3)*8 ..)
    const int xr = tid >> 2, xcg = tid & 3;
    int gxr = r0 + xr; if (gxr >= N_ROWS) gxr = N_ROWS - 1;
    const float* xp = x + (size_t)gxr * 256 + (xcg << 3);

    f16* Xs = (f16*)arena;

    // P1: wave w owns m-tiles {w, w+4, w+8, w+12}
    const f16* wb0 = W1F + (size_t)wave * 4096 + (size_t)lane * 8;   // + mi*16384 + s*512

    f32x4 acc[4][4];                                   // [mi][nt], 64 AGPR
#pragma unroll
    for (int a = 0; a < 4; ++a)
#pragma unroll
        for (int b = 0; b < 4; ++b) acc[a][b] = (f32x4){0.f, 0.f, 0.f, 0.f};

    // prologue: x slices 0,1 into the two sets + af slice 0
    f32x4 pa0 = __builtin_nontemporal_load((const f32x4*)(xp));
    f32x4 pb0 = __builtin_nontemporal_load((const f32x4*)(xp + 4));
    f32x4 pa1 = __builtin_nontemporal_load((const f32x4*)(xp + 32));
    f32x4 pb1 = __builtin_nontemporal_load((const f32x4*)(xp + 36));
    f16x8 afc[4], afn[4];
#pragma unroll
    for (int mi = 0; mi < 4; ++mi)
        afc[mi] = *(const f16x8*)(wb0 + mi * 16384);

    // ---- counted-wait pipelined K-loop (distance-2 x, distance-1 af) ----
#pragma unroll
    for (int s = 0; s < 8; ++s) {
        // commit slice s from set (s&1) — compile-time after full unroll
        const f32x4 ca = (s & 1) ? pa1 : pa0;
        const f32x4 cb = (s & 1) ? pb1 : pb0;
        *(f16x8*)&Xs[xr * LSX + s * 32 + (xcg << 3)] =
            (f16x8){(f16)ca[0],(f16)ca[1],(f16)ca[2],(f16)ca[3],
                    (f16)cb[0],(f16)cb[1],(f16)cb[2],(f16)cb[3]};
        asm volatile("s_waitcnt lgkmcnt(0)" ::: "memory");  // ds_write visible to block
        __builtin_amdgcn_s_barrier();                        // RAW: no vmcnt drain
        asm volatile("" ::: "memory");                       // keep ds_reads below barrier
        if (s < 7) {
            // af first (1-iter slack), then x refill (2-iter slack)
#pragma unroll
            for (int mi = 0; mi < 4; ++mi)
                afn[mi] = *(const f16x8*)(wb0 + mi * 16384 + (s + 1) * 512);
        }
        if (s < 6) {
            if (s & 1) { pa1 = __builtin_nontemporal_load((const f32x4*)(xp + (s + 2) * 32));
                         pb1 = __builtin_nontemporal_load((const f32x4*)(xp + (s + 2) * 32 + 4)); }
            else       { pa0 = __builtin_nontemporal_load((const f32x4*)(xp + (s + 2) * 32));
                         pb0 = __builtin_nontemporal_load((const f32x4*)(xp + (s + 2) * 32 + 4)); }
        }
        f16x8 bf[4];
#pragma unroll
        for (int nt = 0; nt < 4; ++nt)
            bf[nt] = *(const f16x8*)&Xs[(16 * nt + ln) * LSX + s * 32 + quad * 8];
#pragma unroll
        for (int nt = 0; nt < 4; ++nt)
#pragma unroll
            for (int mi = 0; mi < 4; ++mi)
                acc[mi][nt] = __builtin_amdgcn_mfma_f32_16x16x32_f16(afc[mi], bf[nt], acc[mi][nt], 0, 0, 0);
#pragma unroll
        for (int mi = 0; mi < 4; ++mi) afc[mi] = afn[mi];
    }
    __syncthreads();                                   // full drain; arena reused below

    // prefetch W2 frags (coalesced) -- fly during gate epilogue
    f16x8 w2f[2][4];
#pragma unroll
    for (int kc = 0; kc < 4; ++kc) {
        w2f[0][kc] = *(const f16x8*)(W2F + ((size_t)((wave    ) * 4 + kc) * 64 + lane) * 8);
        w2f[1][kc] = *(const f16x8*)(W2F + ((size_t)((wave + 4) * 4 + kc) * 64 + lane) * 8);
    }

    // P1 epilogue: gates -> h1s. D: col(ln)=X row, row(4quad+i)=W col (within m-tile).
    f16* h1s = (f16*)(arena + H1S);
#pragma unroll
    for (int zi = 0; zi < 2; ++zi) {
        const int jg0 = 16 * (wave + 4 * zi) + (quad << 2);
        const float4 zb = *(const float4*)(bz1 + jg0);
        const float4 hb = *(const float4*)(bh1 + jg0);
#pragma unroll
        for (int nt = 0; nt < 4; ++nt) {
            const int row = 16 * nt + ln;
            f16x4 pk;
#pragma unroll
            for (int i = 0; i < 4; ++i)
                pk[i] = (f16)gate(acc[zi][nt][i] + (&zb.x)[i],
                                  acc[zi + 2][nt][i] + (&hb.x)[i]);
            *(f16x4*)&h1s[row * LSH1 + jg0] = pk;
        }
    }
    __syncthreads();

    // ---- P2: h2 = gates(h1 @ W2); wave w: z-cols 16w.., h-cols 64+16w.. ----
    f32x4 acc2[2][4];
#pragma unroll
    for (int a = 0; a < 2; ++a)
#pragma unroll
        for (int b = 0; b < 4; ++b) acc2[a][b] = (f32x4){0.f, 0.f, 0.f, 0.f};
#pragma unroll
    for (int kc = 0; kc < 4; ++kc) {
        f16x8 bf[4];
#pragma unroll
        for (int nt = 0; nt < 4; ++nt)
            bf[nt] = *(const f16x8*)&h1s[(16 * nt + ln) * LSH1 + kc * 32 + quad * 8];
#pragma unroll
        for (int m = 0; m < 2; ++m)
#pragma unroll
            for (int nt = 0; nt < 4; ++nt)
                acc2[m][nt] = __builtin_amdgcn_mfma_f32_16x16x32_f16(w2f[m][kc], bf[nt], acc2[m][nt], 0, 0, 0);
    }
    // h2s region [17408,26624) disjoint from h1s [0,17408): no barrier needed here

    f16* h2s = (f16*)(arena + H2S);
    {
        const int jg0 = 16 * wave + (quad << 2);
        const float4 zb = *(const float4*)(bz2 + jg0);
        const float4 hb = *(const float4*)(bh2 + jg0);
#pragma unroll
        for (int nt = 0; nt < 4; ++nt) {
            const int row = 16 * nt + ln;
            f16x4 pk;
#pragma unroll
            for (int i = 0; i < 4; ++i)
                pk[i] = (f16)gate(acc2[0][nt][i] + (&zb.x)[i],
                                  acc2[1][nt][i] + (&hb.x)[i]);
            *(f16x4*)&h2s[row * LSH2 + jg0] = pk;
        }
    }
    __syncthreads();                                   // cross-wave h2s visibility for P3

    // ---- P3: out = relu(h2 @ wl1 + bl1) @ wl2 + bl2 ; wave w: rows 16w+ln ----
    const float blv = bl1[ln], wlv = wl2[ln], bl2v = bl2[0];
    f16x8 bfr[2];
#pragma unroll
    for (int kc = 0; kc < 2; ++kc)
#pragma unroll
        for (int j = 0; j < 8; ++j)
            bfr[kc][j] = (f16)wl1[(32 * kc + 8 * quad + j) * 16 + ln];

    f32x4 acc3 = (f32x4){0.f, 0.f, 0.f, 0.f};
#pragma unroll
    for (int kc = 0; kc < 2; ++kc) {
        f16x8 af = *(const f16x8*)&h2s[(16 * wave + ln) * LSH2 + kc * 32 + quad * 8];
        acc3 = __builtin_amdgcn_mfma_f32_16x16x32_f16(af, bfr[kc], acc3, 0, 0, 0);
    }
#pragma unroll
    for (int i = 0; i < 4; ++i) {
        float v = fmaxf(acc3[i] + blv, 0.0f) * wlv;
        v += __shfl_xor(v, 1);
        v += __shfl_xor(v, 2);
        v += __shfl_xor(v, 4);
        v += __shfl_xor(v, 8);
        if (ln == 0) {
            const int row = r0 + 16 * wave + (quad << 2) + i;
            if (row < N_ROWS) out[row] = v + bl2v;
        }
    }
}

// ---------- launch ----------
extern "C" void kernel_launch(void* const* d_in, const int* in_sizes, int n_in,
                              void* d_out, int out_size, void* d_ws, size_t ws_size,
                              hipStream_t stream) {
    const float* x   = (const float*)d_in[0];
    const float* wz1 = (const float*)d_in[3];
    const float* bz1 = (const float*)d_in[4];
    const float* wh1 = (const float*)d_in[7];
    const float* bh1 = (const float*)d_in[8];
    const float* wz2 = (const float*)d_in[9];
    const float* bz2 = (const float*)d_in[10];
    const float* wh2 = (const float*)d_in[13];
    const float* bh2 = (const float*)d_in[14];
    const float* wl1 = (const float*)d_in[15];
    const float* bl1 = (const float*)d_in[16];
    const float* wl2 = (const float*)d_in[17];
    const float* bl2 = (const float*)d_in[18];

    char* ws = (char*)d_ws;
    f16* W1F = (f16*)(ws + W1F_OFF);
    f16* W2F = (f16*)(ws + W2F_OFF);
    float* out = (float*)d_out;

    prep_w<<<40, 256, 0, stream>>>(wz1, wh1, wz2, wh2, W1F, W2F);
    fused<<<RT, TPB, 0, stream>>>(x, W1F, W2F, bz1, bh1, bz2, bh2,
                                  wl1, bl1, wl2, bl2, out);
}